// Round 1
// baseline (1189.275 us; speedup 1.0000x reference)
//
#include <hip/hip_runtime.h>

// ResGCN: 3x GCNConv(+BN+ReLU, residual) on N=100k nodes, E=1.6M edges.
// Baseline structure: fp32 everywhere, atomic scatter aggregation.
// b0/b1 skipped (cancelled exactly by following BatchNorm mean subtraction).

#define NN 100000
#define NE 1600000

// ---------------- degree / norm precompute ----------------
__global__ void k_deg_init(float* __restrict__ deg) {
    int i = blockIdx.x * blockDim.x + threadIdx.x;
    if (i < NN) deg[i] = 1.0f;  // self loop
}
__global__ void k_deg_accum(const int* __restrict__ dst, float* __restrict__ deg) {
    int e = blockIdx.x * blockDim.x + threadIdx.x;
    if (e < NE) atomicAdd(&deg[dst[e]], 1.0f);
}
__global__ void k_dinv(float* __restrict__ deg) {
    int i = blockIdx.x * blockDim.x + threadIdx.x;
    if (i < NN) deg[i] = rsqrtf(deg[i]);
}
__global__ void k_norm(const int* __restrict__ src, const int* __restrict__ dst,
                       const float* __restrict__ dinv, float* __restrict__ norm) {
    int e = blockIdx.x * blockDim.x + threadIdx.x;
    if (e < NE) norm[e] = dinv[src[e]] * dinv[dst[e]];
}

// ---------------- fused GEMM (N x 64) @ (64 x 64) ----------------
// MODE 0: Y = X @ W;                agg = dinv^2 * Y   (self-loop init)
// MODE 1: a = relu(bn(X)); side=a;  Y = a @ W;  agg = dinv^2 * Y
template <int MODE>
__launch_bounds__(256)
__global__ void k_gemm64(const float* __restrict__ X, const float* __restrict__ W,
                         const float* __restrict__ scsh, const float* __restrict__ dinv,
                         float* __restrict__ Y, float* __restrict__ side,
                         float* __restrict__ agg) {
    __shared__ float Ws[64 * 64];
    __shared__ float xs[4][64];
    int t = threadIdx.x;
#pragma unroll
    for (int i = 0; i < 16; ++i) Ws[t + 256 * i] = W[t + 256 * i];
    int c = t & 63, rr = t >> 6;
    float scale = 1.f, shift = 0.f;
    if (MODE == 1) { scale = scsh[c]; shift = scsh[64 + c]; }
    int base = blockIdx.x * 256;
    for (int rb = 0; rb < 64; ++rb) {
        int row = base + rb * 4 + rr;
        float v = 0.f;
        if (row < NN) {
            v = X[row * 64 + c];
            if (MODE == 1) {
                v = fmaxf(fmaf(v, scale, shift), 0.f);
                side[row * 64 + c] = v;
            }
        }
        xs[rr][c] = v;
        __syncthreads();
        if (row < NN) {
            float acc = 0.f;
#pragma unroll
            for (int k = 0; k < 64; ++k) acc = fmaf(xs[rr][k], Ws[k * 64 + c], acc);
            Y[row * 64 + c] = acc;
            float d = dinv[row];
            agg[row * 64 + c] = d * d * acc;  // self-loop contribution
        }
        __syncthreads();
    }
}

// ---------------- edge scatter: agg[dst] += norm * h[src]  (64 ch) ----------------
__launch_bounds__(256)
__global__ void k_agg_edges64(const float* __restrict__ h, const int* __restrict__ src,
                              const int* __restrict__ dst, const float* __restrict__ norm,
                              float* __restrict__ agg) {
    int i = blockIdx.x * blockDim.x + threadIdx.x;
    int e = i >> 6, c = i & 63;
    if (e < NE) {
        int s = src[e], d = dst[e];
        float w = norm[e];
        atomicAdd(&agg[d * 64 + c], w * h[s * 64 + c]);
    }
}

// ---------------- BatchNorm stats ----------------
__launch_bounds__(256)
__global__ void k_bn_stats(const float* __restrict__ X, float* __restrict__ stats) {
    __shared__ float sh[512];
    int t = threadIdx.x;
    int c = t & 63, rr = t >> 6;
    float sum = 0.f, sq = 0.f;
    for (int r = blockIdx.x * 4 + rr; r < NN; r += gridDim.x * 4) {
        float v = X[r * 64 + c];
        sum += v;
        sq = fmaf(v, v, sq);
    }
    sh[t] = sum;
    sh[256 + t] = sq;
    __syncthreads();
    if (t < 64) {
        float s = sh[t] + sh[t + 64] + sh[t + 128] + sh[t + 192];
        float q = sh[256 + t] + sh[320 + t] + sh[384 + t] + sh[448 + t];
        atomicAdd(&stats[t], s);
        atomicAdd(&stats[64 + t], q);
    }
}
__global__ void k_bn_final(const float* __restrict__ stats, const float* __restrict__ g,
                           const float* __restrict__ be, float* __restrict__ scsh) {
    int c = threadIdx.x;
    if (c < 64) {
        float mean = stats[c] * (1.0f / NN);
        float var = stats[64 + c] * (1.0f / NN) - mean * mean;
        float sc = g[c] * rsqrtf(var + 1e-5f);
        scsh[c] = sc;
        scsh[64 + c] = be[c] - mean * sc;
    }
}

// ---------------- final layer: h2 = relu(bn(X)) + R;  T = h2 @ W2; out init ----------------
__launch_bounds__(256)
__global__ void k_gemm_out2(const float* __restrict__ X, const float* __restrict__ scsh,
                            const float* __restrict__ R, const float* __restrict__ W2,
                            const float* __restrict__ dinv, const float* __restrict__ b2,
                            float* __restrict__ T, float* __restrict__ out) {
    int t = threadIdx.x;
    int lane = t & 63, wv = t >> 6;
    int row = blockIdx.x * 4 + wv;
    if (row >= NN) return;
    float w0 = W2[lane * 2], w1 = W2[lane * 2 + 1];
    float scale = scsh[lane], shift = scsh[64 + lane];
    float v = X[row * 64 + lane];
    v = fmaxf(fmaf(v, scale, shift), 0.f) + R[row * 64 + lane];
    float p0 = v * w0, p1 = v * w1;
#pragma unroll
    for (int s = 32; s; s >>= 1) {
        p0 += __shfl_xor(p0, s);
        p1 += __shfl_xor(p1, s);
    }
    if (lane == 0) {
        T[row * 2] = p0;
        T[row * 2 + 1] = p1;
        float d = dinv[row];
        out[row * 2] = d * d * p0 + b2[0];
        out[row * 2 + 1] = d * d * p1 + b2[1];
    }
}

__launch_bounds__(256)
__global__ void k_out_edges(const float* __restrict__ T, const int* __restrict__ src,
                            const int* __restrict__ dst, const float* __restrict__ norm,
                            float* __restrict__ out) {
    int i = blockIdx.x * blockDim.x + threadIdx.x;
    int e = i >> 1, oc = i & 1;
    if (e < NE) atomicAdd(&out[dst[e] * 2 + oc], norm[e] * T[src[e] * 2 + oc]);
}

extern "C" void kernel_launch(void* const* d_in, const int* in_sizes, int n_in,
                              void* d_out, int out_size, void* d_ws, size_t ws_size,
                              hipStream_t stream) {
    const float* x  = (const float*)d_in[0];
    const int*   ei = (const int*)d_in[1];
    const int*   src = ei;
    const int*   dst = ei + NE;
    const float* W0 = (const float*)d_in[2];
    const float* g0 = (const float*)d_in[4];
    const float* be0 = (const float*)d_in[5];
    const float* W1 = (const float*)d_in[6];
    const float* g1 = (const float*)d_in[8];
    const float* be1 = (const float*)d_in[9];
    const float* W2 = (const float*)d_in[10];
    const float* b2 = (const float*)d_in[11];
    float* out = (float*)d_out;

    float* deg    = (float*)d_ws;            // N (deg -> dinv in place)
    float* norm   = deg + 102400;            // E
    float* A      = norm + NE;               // N*64  (h0, then h1)
    float* B      = A + NN * 64;             // N*64  (agg0, then agg1)
    float* C      = B + NN * 64;             // N*64  (hres)
    float* T      = C + NN * 64;             // N*2
    float* stats0 = T + NN * 2;              // 128
    float* stats1 = stats0 + 128;            // 128
    float* scsh0  = stats1 + 128;            // 128
    float* scsh1  = scsh0 + 128;             // 128

    hipMemsetAsync(stats0, 0, 256 * sizeof(float), stream);

    k_deg_init<<<(NN + 255) / 256, 256, 0, stream>>>(deg);
    k_deg_accum<<<(NE + 255) / 256, 256, 0, stream>>>(dst, deg);
    k_dinv<<<(NN + 255) / 256, 256, 0, stream>>>(deg);
    k_norm<<<(NE + 255) / 256, 256, 0, stream>>>(src, dst, deg, norm);

    int gemmGrid = (NN + 255) / 256;

    // layer 0: h0 = x @ W0 ; agg0 = selfloop(h0)
    k_gemm64<0><<<gemmGrid, 256, 0, stream>>>(x, W0, nullptr, deg, A, nullptr, B);
    k_agg_edges64<<<(NE * 64) / 256, 256, 0, stream>>>(A, src, dst, norm, B);
    k_bn_stats<<<256, 256, 0, stream>>>(B, stats0);
    k_bn_final<<<1, 64, 0, stream>>>(stats0, g0, be0, scsh0);

    // layer 1: hres = relu(bn(agg0)); h1 = hres @ W1 ; agg1 = selfloop(h1)
    k_gemm64<1><<<gemmGrid, 256, 0, stream>>>(B, W1, scsh0, deg, A, C, B);
    k_agg_edges64<<<(NE * 64) / 256, 256, 0, stream>>>(A, src, dst, norm, B);
    k_bn_stats<<<256, 256, 0, stream>>>(B, stats1);
    k_bn_final<<<1, 64, 0, stream>>>(stats1, g1, be1, scsh1);

    // layer 2: h2 = relu(bn(agg1)) + hres; T = h2 @ W2; out = selfloop + b2
    k_gemm_out2<<<(NN + 3) / 4, 256, 0, stream>>>(B, scsh1, C, W2, deg, b2, T, out);
    k_out_edges<<<(NE * 2 + 255) / 256, 256, 0, stream>>>(T, src, dst, norm, out);
}

// Round 4
// 648.057 us; speedup vs baseline: 1.8351x; 1.8351x over previous
//
#include <hip/hip_runtime.h>

// ResGCN: 3x GCNConv(+BN+ReLU, residual), N=100k nodes, E=1.6M edges.
// R2 (2nd resubmit — two broker timeouts, no bench data yet):
// counting-sort CSR (by dst) + gather-side aggregation (one wave per node).
// dinv pre-multiplied into h so the edge loop needs only csrc (4B) + h row (256B).
// b0/b1 skipped (cancelled exactly by following BatchNorm mean subtraction).

#define NN 100000
#define NE 1600000

// ---------------- CSR build ----------------
__global__ void k_hist(const int* __restrict__ dst, int* __restrict__ cnt) {
    int e = blockIdx.x * blockDim.x + threadIdx.x;
    if (e < NE) atomicAdd(&cnt[dst[e]], 1);
}

// per-block (1024 elems) sums; also dinv[i] = rsqrt(cnt[i]+1)
__global__ void k_scan1(const int* __restrict__ cnt, int* __restrict__ bsum,
                        float* __restrict__ dinv) {
    __shared__ int sh[256];
    int b = blockIdx.x, t = threadIdx.x;
    int base = b * 1024 + t * 4;
    int s = 0;
    for (int k = 0; k < 4; ++k) {
        int i = base + k;
        if (i < NN) {
            int c = cnt[i];
            s += c;
            dinv[i] = rsqrtf((float)(c + 1));
        }
    }
    sh[t] = s;
    __syncthreads();
    for (int st = 128; st; st >>= 1) {
        if (t < st) sh[t] += sh[t + st];
        __syncthreads();
    }
    if (t == 0) bsum[b] = sh[0];
}
__global__ void k_scan2(const int* __restrict__ bsum, int* __restrict__ boff, int nb) {
    if (threadIdx.x == 0) {
        int acc = 0;
        for (int i = 0; i < nb; ++i) { boff[i] = acc; acc += bsum[i]; }
    }
}
__global__ void k_scan3(const int* __restrict__ cnt, const int* __restrict__ boff,
                        int* __restrict__ rowstart) {
    __shared__ int sh[256];
    int b = blockIdx.x, t = threadIdx.x;
    int base = b * 1024 + t * 4;
    int v[4];
    int s = 0;
    for (int k = 0; k < 4; ++k) {
        int i = base + k;
        v[k] = (i < NN) ? cnt[i] : 0;
        s += v[k];
    }
    sh[t] = s;
    __syncthreads();
    if (t == 0) {
        int acc = boff[b];
        for (int i = 0; i < 256; ++i) { int x = sh[i]; sh[i] = acc; acc += x; }
    }
    __syncthreads();
    int acc = sh[t];
    for (int k = 0; k < 4; ++k) {
        int i = base + k;
        if (i < NN) rowstart[i] = acc;
        acc += v[k];
    }
}
__global__ void k_fill(const int* __restrict__ src, const int* __restrict__ dst,
                       const int* __restrict__ rowstart, int* __restrict__ cursor,
                       int* __restrict__ csrc) {
    int e = blockIdx.x * blockDim.x + threadIdx.x;
    if (e < NE) {
        int d = dst[e];
        int p = rowstart[d] + atomicAdd(&cursor[d], 1);
        csrc[p] = src[e];
    }
}

// ---------------- fused GEMM (N x 64) @ (64 x 64), epilogue premult by dinv ----------------
// MODE 0: Yp = dinv * (X @ W)
// MODE 1: a = relu(bn(X)); side = a; Yp = dinv * (a @ W)
template <int MODE>
__launch_bounds__(256)
__global__ void k_gemm64(const float* __restrict__ X, const float* __restrict__ W,
                         const float* __restrict__ scsh, const float* __restrict__ dinv,
                         float* __restrict__ Yp, float* __restrict__ side) {
    __shared__ float Ws[64 * 64];
    __shared__ float xs[4][64];
    int t = threadIdx.x;
#pragma unroll
    for (int i = 0; i < 16; ++i) Ws[t + 256 * i] = W[t + 256 * i];
    int c = t & 63, rr = t >> 6;
    float scale = 1.f, shift = 0.f;
    if (MODE == 1) { scale = scsh[c]; shift = scsh[64 + c]; }
    int base = blockIdx.x * 256;
    for (int rb = 0; rb < 64; ++rb) {
        int row = base + rb * 4 + rr;
        float v = 0.f;
        if (row < NN) {
            v = X[row * 64 + c];
            if (MODE == 1) {
                v = fmaxf(fmaf(v, scale, shift), 0.f);
                side[row * 64 + c] = v;
            }
        }
        xs[rr][c] = v;
        __syncthreads();
        if (row < NN) {
            float acc = 0.f;
#pragma unroll
            for (int k = 0; k < 64; ++k) acc = fmaf(xs[rr][k], Ws[k * 64 + c], acc);
            Yp[row * 64 + c] = dinv[row] * acc;
        }
        __syncthreads();
    }
}

// ---------------- CSR aggregation: agg[d] = dinv[d]*(Yp[d] + sum Yp[src]) ----------------
__launch_bounds__(256)
__global__ void k_agg_csr(const float* __restrict__ Yp, const int* __restrict__ rowstart,
                          const int* __restrict__ cnt, const int* __restrict__ csrc,
                          const float* __restrict__ dinv, float* __restrict__ agg) {
    int wid = (blockIdx.x * blockDim.x + threadIdx.x) >> 6;  // node
    int lane = threadIdx.x & 63;
    if (wid >= NN) return;
    int grp = lane >> 4;  // 0..3: edge slot within iteration
    int l16 = lane & 15;  // float4 channel quad
    int beg = rowstart[wid], n = cnt[wid];
    float4 acc = {0.f, 0.f, 0.f, 0.f};
    if (grp == 0) acc = ((const float4*)(Yp + (long)wid * 64))[l16];  // self loop
    for (int j = grp; j < n; j += 4) {
        int s = csrc[beg + j];
        float4 v = ((const float4*)(Yp + (long)s * 64))[l16];
        acc.x += v.x; acc.y += v.y; acc.z += v.z; acc.w += v.w;
    }
#pragma unroll
    for (int m = 16; m <= 32; m <<= 1) {
        acc.x += __shfl_xor(acc.x, m);
        acc.y += __shfl_xor(acc.y, m);
        acc.z += __shfl_xor(acc.z, m);
        acc.w += __shfl_xor(acc.w, m);
    }
    if (grp == 0) {
        float d = dinv[wid];
        float4 r = {acc.x * d, acc.y * d, acc.z * d, acc.w * d};
        ((float4*)(agg + (long)wid * 64))[l16] = r;
    }
}

// ---------------- BatchNorm stats ----------------
__launch_bounds__(256)
__global__ void k_bn_stats(const float* __restrict__ X, float* __restrict__ stats) {
    __shared__ float sh[512];
    int t = threadIdx.x;
    int c = t & 63, rr = t >> 6;
    float sum = 0.f, sq = 0.f;
    for (int r = blockIdx.x * 4 + rr; r < NN; r += gridDim.x * 4) {
        float v = X[r * 64 + c];
        sum += v;
        sq = fmaf(v, v, sq);
    }
    sh[t] = sum;
    sh[256 + t] = sq;
    __syncthreads();
    if (t < 64) {
        float s = sh[t] + sh[t + 64] + sh[t + 128] + sh[t + 192];
        float q = sh[256 + t] + sh[320 + t] + sh[384 + t] + sh[448 + t];
        atomicAdd(&stats[t], s);
        atomicAdd(&stats[64 + t], q);
    }
}
__global__ void k_bn_final(const float* __restrict__ stats, const float* __restrict__ g,
                           const float* __restrict__ be, float* __restrict__ scsh) {
    int c = threadIdx.x;
    if (c < 64) {
        float mean = stats[c] * (1.0f / NN);
        float var = stats[64 + c] * (1.0f / NN) - mean * mean;
        float sc = g[c] * rsqrtf(var + 1e-5f);
        scsh[c] = sc;
        scsh[64 + c] = be[c] - mean * sc;
    }
}

// ---------------- final layer GEMM: Tp = dinv * ((relu(bn(X)) + R) @ W2) ----------------
__launch_bounds__(256)
__global__ void k_gemm_out2(const float* __restrict__ X, const float* __restrict__ scsh,
                            const float* __restrict__ R, const float* __restrict__ W2,
                            const float* __restrict__ dinv, float* __restrict__ Tp) {
    int t = threadIdx.x;
    int lane = t & 63, wv = t >> 6;
    int row = blockIdx.x * 4 + wv;
    if (row >= NN) return;
    float w0 = W2[lane * 2], w1 = W2[lane * 2 + 1];
    float scale = scsh[lane], shift = scsh[64 + lane];
    float v = X[row * 64 + lane];
    v = fmaxf(fmaf(v, scale, shift), 0.f) + R[row * 64 + lane];
    float p0 = v * w0, p1 = v * w1;
#pragma unroll
    for (int s = 32; s; s >>= 1) {
        p0 += __shfl_xor(p0, s);
        p1 += __shfl_xor(p1, s);
    }
    if (lane == 0) {
        float d = dinv[row];
        Tp[row * 2] = d * p0;
        Tp[row * 2 + 1] = d * p1;
    }
}

// ---------------- final CSR aggregation, 2 channels, 8 lanes/node ----------------
__launch_bounds__(256)
__global__ void k_out_csr(const float* __restrict__ Tp, const int* __restrict__ rowstart,
                          const int* __restrict__ cnt, const int* __restrict__ csrc,
                          const float* __restrict__ dinv, const float* __restrict__ b2,
                          float* __restrict__ out) {
    int id = blockIdx.x * blockDim.x + threadIdx.x;
    int node = id >> 3, l = id & 7;
    if (node >= NN) return;
    int beg = rowstart[node], n = cnt[node];
    float a0 = 0.f, a1 = 0.f;
    if (l == 0) { a0 = Tp[node * 2]; a1 = Tp[node * 2 + 1]; }  // self loop
    for (int j = l; j < n; j += 8) {
        int s = csrc[beg + j];
        a0 += Tp[s * 2];
        a1 += Tp[s * 2 + 1];
    }
#pragma unroll
    for (int m = 1; m < 8; m <<= 1) {
        a0 += __shfl_xor(a0, m);
        a1 += __shfl_xor(a1, m);
    }
    if (l == 0) {
        float d = dinv[node];
        out[node * 2] = d * a0 + b2[0];
        out[node * 2 + 1] = d * a1 + b2[1];
    }
}

extern "C" void kernel_launch(void* const* d_in, const int* in_sizes, int n_in,
                              void* d_out, int out_size, void* d_ws, size_t ws_size,
                              hipStream_t stream) {
    const float* x   = (const float*)d_in[0];
    const int*   ei  = (const int*)d_in[1];
    const int*   src = ei;
    const int*   dst = ei + NE;
    const float* W0  = (const float*)d_in[2];
    const float* g0  = (const float*)d_in[4];
    const float* be0 = (const float*)d_in[5];
    const float* W1  = (const float*)d_in[6];
    const float* g1  = (const float*)d_in[8];
    const float* be1 = (const float*)d_in[9];
    const float* W2  = (const float*)d_in[10];
    const float* b2  = (const float*)d_in[11];
    float* out = (float*)d_out;

    int*   cnt      = (int*)d_ws;             // N
    int*   cursor   = cnt + NN;               // N  (zeroed together with cnt)
    int*   rowstart = cursor + NN;            // N
    int*   bsum     = rowstart + NN;          // 128
    int*   boff     = bsum + 128;             // 128
    int*   csrc     = boff + 128;             // E
    float* dinv     = (float*)(csrc + NE);    // N
    float* A        = dinv + NN;              // N*64  (Yp)
    float* B        = A + NN * 64;            // N*64  (agg)
    float* C        = B + NN * 64;            // N*64  (hres)
    float* Tp       = C + NN * 64;            // N*2
    float* stats0   = Tp + NN * 2;            // 128
    float* stats1   = stats0 + 128;           // 128
    float* scsh0    = stats1 + 128;           // 128
    float* scsh1    = scsh0 + 128;            // 128

    hipMemsetAsync(cnt, 0, 2 * NN * sizeof(int), stream);       // cnt + cursor
    hipMemsetAsync(stats0, 0, 256 * sizeof(float), stream);

    const int NB = (NN + 1023) / 1024;  // 98
    k_hist<<<(NE + 255) / 256, 256, 0, stream>>>(dst, cnt);
    k_scan1<<<NB, 256, 0, stream>>>(cnt, bsum, dinv);
    k_scan2<<<1, 64, 0, stream>>>(bsum, boff, NB);
    k_scan3<<<NB, 256, 0, stream>>>(cnt, boff, rowstart);
    k_fill<<<(NE + 255) / 256, 256, 0, stream>>>(src, dst, rowstart, cursor, csrc);

    int gemmGrid = (NN + 255) / 256;
    int aggGrid  = (NN * 64) / 256;   // one wave per node, exact

    // layer 0
    k_gemm64<0><<<gemmGrid, 256, 0, stream>>>(x, W0, nullptr, dinv, A, nullptr);
    k_agg_csr<<<aggGrid, 256, 0, stream>>>(A, rowstart, cnt, csrc, dinv, B);
    k_bn_stats<<<256, 256, 0, stream>>>(B, stats0);
    k_bn_final<<<1, 64, 0, stream>>>(stats0, g0, be0, scsh0);

    // layer 1
    k_gemm64<1><<<gemmGrid, 256, 0, stream>>>(B, W1, scsh0, dinv, A, C);
    k_agg_csr<<<aggGrid, 256, 0, stream>>>(A, rowstart, cnt, csrc, dinv, B);
    k_bn_stats<<<256, 256, 0, stream>>>(B, stats1);
    k_bn_final<<<1, 64, 0, stream>>>(stats1, g1, be1, scsh1);

    // layer 2
    k_gemm_out2<<<(NN + 3) / 4, 256, 0, stream>>>(B, scsh1, C, W2, dinv, Tp);
    k_out_csr<<<(NN * 8 + 255) / 256, 256, 0, stream>>>(Tp, rowstart, cnt, csrc, dinv, b2, out);
}